// Round 3
// baseline (59.056 us; speedup 1.0000x reference)
//
#include <hip/hip_runtime.h>
#include <hip/hip_bf16.h>

typedef __attribute__((ext_vector_type(8))) short bf16x8;
typedef __attribute__((ext_vector_type(4))) float f32x4;
typedef __attribute__((ext_vector_type(4))) unsigned short u16x4;

static constexpr int D = 256;
static constexpr float INV_T = 2.0f;                 // 1 / temperature(0.5)
static constexpr float KEXP2 = 2.8853900817779268f;  // 2 * log2(e): exp(2x) = 2^(KEXP2*x)
static constexpr int BM = 256;                       // rows per block in k_main (4 waves x 64)
static constexpr int BN = 32;                        // cols per step
static constexpr int CSPLIT = 16;                    // column splits across grid
static constexpr int NSTEP = 16;                     // (8192/CSPLIT)/BN

__device__ inline unsigned short f2bf(float x) {
    unsigned int u = __builtin_bit_cast(unsigned int, x);
    u += 0x7fffu + ((u >> 16) & 1u);   // round-to-nearest-even
    return (unsigned short)(u >> 16);
}
__device__ inline float bf2f(unsigned short h) {
    unsigned int u = ((unsigned int)h) << 16;
    return __builtin_bit_cast(float, u);
}
__device__ inline float fexp2(float x) {
#if __has_builtin(__builtin_amdgcn_exp2f)
    return __builtin_amdgcn_exp2f(x);
#else
    return exp2f(x);
#endif
}

// Kernel 1: per pair i in [0,B): normalize rows i and i+B to bf16,
// rowsum init = -exp(2*selfdot) (diagonal removal), positive-pair dot ->
// per-block partial (no global atomics).
__global__ void k_norm(const float* __restrict__ zi, const float* __restrict__ zj,
                       unsigned short* __restrict__ zn, float* __restrict__ rowsum,
                       float* __restrict__ pos_partial, int B) {
    __shared__ float red[4];
    const int lane = threadIdx.x & 63;
    const int wv = threadIdx.x >> 6;
    const int i = blockIdx.x * 4 + wv;       // pair index
    if (i < B) {
        float4 vi = reinterpret_cast<const float4*>(zi + (size_t)i * D)[lane];
        float4 vj = reinterpret_cast<const float4*>(zj + (size_t)i * D)[lane];
        float ssi = vi.x * vi.x + vi.y * vi.y + vi.z * vi.z + vi.w * vi.w;
        float ssj = vj.x * vj.x + vj.y * vj.y + vj.z * vj.z + vj.w * vj.w;
#pragma unroll
        for (int off = 32; off >= 1; off >>= 1) {
            ssi += __shfl_xor(ssi, off, 64);
            ssj += __shfl_xor(ssj, off, 64);
        }
        float rni = rsqrtf(ssi), rnj = rsqrtf(ssj);
        unsigned short a0 = f2bf(vi.x * rni), a1 = f2bf(vi.y * rni);
        unsigned short a2 = f2bf(vi.z * rni), a3 = f2bf(vi.w * rni);
        unsigned short b0 = f2bf(vj.x * rnj), b1 = f2bf(vj.y * rnj);
        unsigned short b2 = f2bf(vj.z * rnj), b3 = f2bf(vj.w * rnj);
        u16x4 oa; oa.x = a0; oa.y = a1; oa.z = a2; oa.w = a3;
        u16x4 ob; ob.x = b0; ob.y = b1; ob.z = b2; ob.w = b3;
        *reinterpret_cast<u16x4*>(zn + (size_t)i * D + lane * 4) = oa;
        *reinterpret_cast<u16x4*>(zn + (size_t)(i + B) * D + lane * 4) = ob;
        // self-dots + pair-dot with bf16-rounded values (match MFMA exactly)
        float fa0 = bf2f(a0), fa1 = bf2f(a1), fa2 = bf2f(a2), fa3 = bf2f(a3);
        float fb0 = bf2f(b0), fb1 = bf2f(b1), fb2 = bf2f(b2), fb3 = bf2f(b3);
        float sdi = fa0 * fa0 + fa1 * fa1 + fa2 * fa2 + fa3 * fa3;
        float sdj = fb0 * fb0 + fb1 * fb1 + fb2 * fb2 + fb3 * fb3;
        float pd  = fa0 * fb0 + fa1 * fb1 + fa2 * fb2 + fa3 * fb3;
#pragma unroll
        for (int off = 32; off >= 1; off >>= 1) {
            sdi += __shfl_xor(sdi, off, 64);
            sdj += __shfl_xor(sdj, off, 64);
            pd  += __shfl_xor(pd, off, 64);
        }
        if (lane == 0) {
            rowsum[i]     = -fexp2(KEXP2 * sdi);
            rowsum[i + B] = -fexp2(KEXP2 * sdj);
            red[wv] = pd;
        }
    } else if (lane == 0) {
        red[wv] = 0.f;
    }
    __syncthreads();
    if (threadIdx.x == 0)
        pos_partial[blockIdx.x] = 2.0f * INV_T * (red[0] + red[1] + red[2] + red[3]);
}

// Kernel 2: sim tile via MFMA, exp, accumulate row sums.
// B-tile stored in LDS in MFMA-FRAGMENT order: lds[frag][lane][8], so both the
// staging ds_write and the compute ds_read are linear (conflict-free) and the
// compute read needs one addr VGPR + immediate offsets.
// frag f = kk*2 + h; element lds[f][lane][e] = zn[j0 + (lane&15) + h*16][kk*32 + (lane>>4)*8 + e]
__global__ __launch_bounds__(256, 2)
void k_main(const unsigned short* __restrict__ zn, float* __restrict__ rowsum, int N) {
    __shared__ __align__(16) unsigned short lds[2][16][64][8];   // 32 KB
    const int tid = threadIdx.x;
    const int lane = tid & 63, wv = tid >> 6;
    const int l15 = lane & 15, lhi = lane >> 4;
    const int rb = blockIdx.x >> 4;              // row block 0..31
    const int cb = blockIdx.x & (CSPLIT - 1);    // column split 0..15
    const int i0 = rb * BM;
    const int j0base = cb * (N / CSPLIT);

    // A fragments: rows i0 + wv*64 + r*16 + l15, k = kk*32 + lhi*8 (+e)
    bf16x8 a[4][8];
    {
        const unsigned short* ab = zn + (size_t)(i0 + wv * 64 + l15) * D + lhi * 8;
#pragma unroll
        for (int r = 0; r < 4; ++r)
#pragma unroll
            for (int kk = 0; kk < 8; ++kk)
                a[r][kk] = *reinterpret_cast<const bf16x8*>(ab + r * 16 * D + kk * 32);
    }

    // staging map: chunk i -> fragment f = wv + 4*i (uniform per wave), lane ln = lane
    int grow[4], gcol[4];
#pragma unroll
    for (int i = 0; i < 4; ++i) {
        int f = (tid + 256 * i) >> 6;            // == wv + 4*i
        grow[i] = (lane & 15) + (f & 1) * 16;    // zn row offset within col tile
        gcol[i] = (f >> 1) * 32 + (lane >> 4) * 8;
    }

    bf16x8* ldsv = reinterpret_cast<bf16x8*>(lds);

    float rs[4][4];
#pragma unroll
    for (int r = 0; r < 4; ++r)
#pragma unroll
        for (int q = 0; q < 4; ++q) rs[r][q] = 0.f;

    bf16x8 st[4];
    // prologue: stage step 0 into buffer 0 (linear LDS writes)
#pragma unroll
    for (int i = 0; i < 4; ++i)
        st[i] = *reinterpret_cast<const bf16x8*>(zn + (size_t)(j0base + grow[i]) * D + gcol[i]);
#pragma unroll
    for (int i = 0; i < 4; ++i)
        ldsv[tid + 256 * i] = st[i];
    __syncthreads();

    for (int s = 0; s < NSTEP; ++s) {
        const int buf = s & 1;
        if (s + 1 < NSTEP) {   // issue next tile's global loads early (hide under MFMA)
            int j0n = j0base + (s + 1) * BN;
#pragma unroll
            for (int i = 0; i < 4; ++i)
                st[i] = *reinterpret_cast<const bf16x8*>(zn + (size_t)(j0n + grow[i]) * D + gcol[i]);
        }
        f32x4 acc[4][2];
#pragma unroll
        for (int r = 0; r < 4; ++r)
#pragma unroll
            for (int c = 0; c < 2; ++c) acc[r][c] = (f32x4){0.f, 0.f, 0.f, 0.f};

        const bf16x8* bv = ldsv + buf * 1024;
#pragma unroll
        for (int kk = 0; kk < 8; ++kk) {
            bf16x8 b0 = bv[(kk * 2 + 0) * 64 + lane];   // linear: lane*16B + imm
            bf16x8 b1 = bv[(kk * 2 + 1) * 64 + lane];
#pragma unroll
            for (int r = 0; r < 4; ++r) {
                acc[r][0] = __builtin_amdgcn_mfma_f32_16x16x32_bf16(a[r][kk], b0, acc[r][0], 0, 0, 0);
                acc[r][1] = __builtin_amdgcn_mfma_f32_16x16x32_bf16(a[r][kk], b1, acc[r][1], 0, 0, 0);
            }
        }
        // epilogue: single-instr exp2 (exp(2x) = 2^(KEXP2*x)); diagonal handled in k_norm
#pragma unroll
        for (int r = 0; r < 4; ++r)
#pragma unroll
            for (int c = 0; c < 2; ++c)
#pragma unroll
                for (int q = 0; q < 4; ++q)
                    rs[r][q] += fexp2(KEXP2 * acc[r][c][q]);

        if (s + 1 < NSTEP) {   // write next tile into the other buffer (linear)
#pragma unroll
            for (int i = 0; i < 4; ++i)
                ldsv[(buf ^ 1) * 1024 + tid + 256 * i] = st[i];
        }
        __syncthreads();
    }

    // reduce rs across the 16 lanes sharing each row, then one atomic per row
    // (16 column-split blocks hit DISTINCT addresses per row -> low contention)
#pragma unroll
    for (int r = 0; r < 4; ++r)
#pragma unroll
        for (int q = 0; q < 4; ++q) {
            float v = rs[r][q];
            v += __shfl_xor(v, 1, 64);
            v += __shfl_xor(v, 2, 64);
            v += __shfl_xor(v, 4, 64);
            v += __shfl_xor(v, 8, 64);
            if (l15 == 0)
                atomicAdd(&rowsum[i0 + wv * 64 + r * 16 + lhi * 4 + q], v);
        }
}

// Kernel 3: loss = (sum_i log(rowsum_i) - sum_b pos_partial_b) / N
__global__ void k_final(const float* __restrict__ rowsum, const float* __restrict__ pos_partial,
                        int n_partial, float* __restrict__ out, int N) {
    __shared__ float red[4];
    int lane = threadIdx.x & 63, wv = threadIdx.x >> 6;
    float local = 0.f;
    for (int i = threadIdx.x; i < N; i += 256) local += __logf(rowsum[i]);
    for (int i = threadIdx.x; i < n_partial; i += 256) local -= pos_partial[i];
#pragma unroll
    for (int off = 32; off >= 1; off >>= 1) local += __shfl_xor(local, off, 64);
    if (lane == 0) red[wv] = local;
    __syncthreads();
    if (threadIdx.x == 0) {
        out[0] = (red[0] + red[1] + red[2] + red[3]) / (float)N;
    }
}

extern "C" void kernel_launch(void* const* d_in, const int* in_sizes, int n_in,
                              void* d_out, int out_size, void* d_ws, size_t ws_size,
                              hipStream_t stream) {
    const float* zi = (const float*)d_in[0];
    const float* zj = (const float*)d_in[1];
    const int B = in_sizes[0] / D;   // 4096
    const int N = 2 * B;             // 8192

    unsigned short* zn = (unsigned short*)d_ws;                       // N*D bf16 = 4 MB
    float* rowsum = (float*)((char*)d_ws + (size_t)N * D * 2);        // N floats
    float* pos_partial = rowsum + N;                                  // B/4 floats

    float* out = (float*)d_out;

    const int npb = B / 4;  // k_norm blocks == pos partials
    hipLaunchKernelGGL(k_norm, dim3(npb), dim3(256), 0, stream, zi, zj, zn, rowsum, pos_partial, B);
    hipLaunchKernelGGL(k_main, dim3((N / BM) * CSPLIT), dim3(256), 0, stream, zn, rowsum, N);
    hipLaunchKernelGGL(k_final, dim3(1), dim3(256), 0, stream, rowsum, pos_partial, npb, out, N);
}

// Round 4
// 56.872 us; speedup vs baseline: 1.0384x; 1.0384x over previous
//
#include <hip/hip_runtime.h>
#include <hip/hip_bf16.h>

typedef __attribute__((ext_vector_type(8))) short bf16x8;
typedef __attribute__((ext_vector_type(4))) float f32x4;
typedef __attribute__((ext_vector_type(4))) unsigned short u16x4;

static constexpr int D = 256;
static constexpr float INV_T = 2.0f;                 // 1 / temperature(0.5)
static constexpr float KEXP2 = 2.8853900817779268f;  // 2 * log2(e): exp(2x) = 2^(KEXP2*x)
static constexpr int BM = 256;                       // tile side (4 waves x 64 rows)
static constexpr int BN = 32;                        // cols per step
static constexpr int TTILE = 32;                     // 8192 / 256
static constexpr int NBLK = TTILE * (TTILE + 1) / 2; // 528 upper-triangle tiles
static constexpr int NSTEP = BM / BN;                // 8

__device__ inline unsigned short f2bf(float x) {
    unsigned int u = __builtin_bit_cast(unsigned int, x);
    u += 0x7fffu + ((u >> 16) & 1u);   // round-to-nearest-even
    return (unsigned short)(u >> 16);
}
__device__ inline float bf2f(unsigned short h) {
    unsigned int u = ((unsigned int)h) << 16;
    return __builtin_bit_cast(float, u);
}
__device__ inline float fexp2(float x) {
#if __has_builtin(__builtin_amdgcn_exp2f)
    return __builtin_amdgcn_exp2f(x);
#else
    return exp2f(x);
#endif
}
// Keep-alive: asm output can't be rematerialized -> forces the loaded A
// fragment to stay register-resident across the K-loop (R3 showed VGPR=108
// < 128 needed for A => compiler was re-fetching A from L2 every step).
__device__ inline void keepv(bf16x8& x) { asm volatile("" : "+v"(x)); }

// Kernel 1: per pair i in [0,B): normalize rows i and i+B to bf16,
// rowsum init = -exp(2*selfdot) (diagonal removal), positive-pair dot ->
// per-block partial (no global atomics).
__global__ void k_norm(const float* __restrict__ zi, const float* __restrict__ zj,
                       unsigned short* __restrict__ zn, float* __restrict__ rowsum,
                       float* __restrict__ pos_partial, int B) {
    __shared__ float red[4];
    const int lane = threadIdx.x & 63;
    const int wv = threadIdx.x >> 6;
    const int i = blockIdx.x * 4 + wv;       // pair index
    if (i < B) {
        float4 vi = reinterpret_cast<const float4*>(zi + (size_t)i * D)[lane];
        float4 vj = reinterpret_cast<const float4*>(zj + (size_t)i * D)[lane];
        float ssi = vi.x * vi.x + vi.y * vi.y + vi.z * vi.z + vi.w * vi.w;
        float ssj = vj.x * vj.x + vj.y * vj.y + vj.z * vj.z + vj.w * vj.w;
#pragma unroll
        for (int off = 32; off >= 1; off >>= 1) {
            ssi += __shfl_xor(ssi, off, 64);
            ssj += __shfl_xor(ssj, off, 64);
        }
        float rni = rsqrtf(ssi), rnj = rsqrtf(ssj);
        unsigned short a0 = f2bf(vi.x * rni), a1 = f2bf(vi.y * rni);
        unsigned short a2 = f2bf(vi.z * rni), a3 = f2bf(vi.w * rni);
        unsigned short b0 = f2bf(vj.x * rnj), b1 = f2bf(vj.y * rnj);
        unsigned short b2 = f2bf(vj.z * rnj), b3 = f2bf(vj.w * rnj);
        u16x4 oa; oa.x = a0; oa.y = a1; oa.z = a2; oa.w = a3;
        u16x4 ob; ob.x = b0; ob.y = b1; ob.z = b2; ob.w = b3;
        *reinterpret_cast<u16x4*>(zn + (size_t)i * D + lane * 4) = oa;
        *reinterpret_cast<u16x4*>(zn + (size_t)(i + B) * D + lane * 4) = ob;
        // self-dots + pair-dot with bf16-rounded values (match MFMA closely)
        float fa0 = bf2f(a0), fa1 = bf2f(a1), fa2 = bf2f(a2), fa3 = bf2f(a3);
        float fb0 = bf2f(b0), fb1 = bf2f(b1), fb2 = bf2f(b2), fb3 = bf2f(b3);
        float sdi = fa0 * fa0 + fa1 * fa1 + fa2 * fa2 + fa3 * fa3;
        float sdj = fb0 * fb0 + fb1 * fb1 + fb2 * fb2 + fb3 * fb3;
        float pd  = fa0 * fb0 + fa1 * fb1 + fa2 * fb2 + fa3 * fb3;
#pragma unroll
        for (int off = 32; off >= 1; off >>= 1) {
            sdi += __shfl_xor(sdi, off, 64);
            sdj += __shfl_xor(sdj, off, 64);
            pd  += __shfl_xor(pd, off, 64);
        }
        if (lane == 0) {
            rowsum[i]     = -fexp2(KEXP2 * sdi);
            rowsum[i + B] = -fexp2(KEXP2 * sdj);
            red[wv] = pd;
        }
    } else if (lane == 0) {
        red[wv] = 0.f;
    }
    __syncthreads();
    if (threadIdx.x == 0)
        pos_partial[blockIdx.x] = 2.0f * INV_T * (red[0] + red[1] + red[2] + red[3]);
}

// Kernel 2: upper-triangle 256x256 tiles of sim via MFMA; exp; row-sums to
// tile-i rows; for off-diagonal tiles also column-sums to tile-j rows
// (symmetry: sim = sim^T halves total work).
// B-tile in LDS in MFMA-fragment order (linear writes/reads, conflict-free).
__global__ __launch_bounds__(256, 2)
void k_main(const unsigned short* __restrict__ zn, float* __restrict__ rowsum, int N) {
    __shared__ __align__(16) unsigned short lds[2][16][64][8];   // 32 KB
    __shared__ float cs_lds[4][256];                             // 4 KB (per-wave colsum)
    const int tid = threadIdx.x;
    const int lane = tid & 63, wv = tid >> 6;
    const int l15 = lane & 15, lhi = lane >> 4;

    // decode upper-triangle tile (ti <= tj)
    int ti = 0, rem = blockIdx.x;
    while (rem >= TTILE - ti) { rem -= TTILE - ti; ++ti; }
    const int tj = ti + rem;
    const bool is_diag = (ti == tj);
    const int i0 = ti * BM;
    const int j0base = tj * BM;

    if (!is_diag)
        for (int i = tid; i < 4 * 256; i += 256) ((float*)cs_lds)[i] = 0.f;

    // A fragments: rows i0 + wv*64 + r*16 + l15, k = kk*32 + lhi*8 (+e)
    bf16x8 a[4][8];
    {
        const unsigned short* ab = zn + (size_t)(i0 + wv * 64 + l15) * D + lhi * 8;
#pragma unroll
        for (int r = 0; r < 4; ++r)
#pragma unroll
            for (int kk = 0; kk < 8; ++kk) {
                a[r][kk] = *reinterpret_cast<const bf16x8*>(ab + r * 16 * D + kk * 32);
                keepv(a[r][kk]);
            }
    }

    // staging map: chunk i -> fragment f = wv + 4*i (uniform per wave)
    int grow[4], gcol[4];
#pragma unroll
    for (int i = 0; i < 4; ++i) {
        int f = (tid + 256 * i) >> 6;            // == wv + 4*i
        grow[i] = (lane & 15) + (f & 1) * 16;    // zn row offset within col tile
        gcol[i] = (f >> 1) * 32 + (lane >> 4) * 8;
    }

    bf16x8* ldsv = reinterpret_cast<bf16x8*>(lds);

    float rs[4][4];
#pragma unroll
    for (int r = 0; r < 4; ++r)
#pragma unroll
        for (int q = 0; q < 4; ++q) rs[r][q] = 0.f;

    bf16x8 st[4];
    // prologue: stage step 0 into buffer 0 (linear LDS writes)
#pragma unroll
    for (int i = 0; i < 4; ++i)
        st[i] = *reinterpret_cast<const bf16x8*>(zn + (size_t)(j0base + grow[i]) * D + gcol[i]);
#pragma unroll
    for (int i = 0; i < 4; ++i)
        ldsv[tid + 256 * i] = st[i];
    __syncthreads();

    for (int s = 0; s < NSTEP; ++s) {
        const int buf = s & 1;
        if (s + 1 < NSTEP) {   // issue next tile's global loads early
            int j0n = j0base + (s + 1) * BN;
#pragma unroll
            for (int i = 0; i < 4; ++i)
                st[i] = *reinterpret_cast<const bf16x8*>(zn + (size_t)(j0n + grow[i]) * D + gcol[i]);
        }
        f32x4 acc[4][2];
#pragma unroll
        for (int r = 0; r < 4; ++r)
#pragma unroll
            for (int c = 0; c < 2; ++c) acc[r][c] = (f32x4){0.f, 0.f, 0.f, 0.f};

        const bf16x8* bv = ldsv + buf * 1024;
#pragma unroll
        for (int kk = 0; kk < 8; ++kk) {
            bf16x8 b0 = bv[(kk * 2 + 0) * 64 + lane];   // linear: lane*16B + imm
            bf16x8 b1 = bv[(kk * 2 + 1) * 64 + lane];
#pragma unroll
            for (int r = 0; r < 4; ++r) {
                acc[r][0] = __builtin_amdgcn_mfma_f32_16x16x32_bf16(a[r][kk], b0, acc[r][0], 0, 0, 0);
                acc[r][1] = __builtin_amdgcn_mfma_f32_16x16x32_bf16(a[r][kk], b1, acc[r][1], 0, 0, 0);
            }
        }
        // epilogue: e = exp(2*sim) via single v_exp; row-sums always,
        // col-sums only for off-diagonal tiles
        if (!is_diag) {
            float cs0 = 0.f, cs1 = 0.f;
#pragma unroll
            for (int r = 0; r < 4; ++r)
#pragma unroll
                for (int q = 0; q < 4; ++q) {
                    float e0 = fexp2(KEXP2 * acc[r][0][q]);
                    float e1 = fexp2(KEXP2 * acc[r][1][q]);
                    rs[r][q] += e0 + e1;
                    cs0 += e0; cs1 += e1;
                }
            // reduce over lhi (rows within fragment quarters)
            cs0 += __shfl_xor(cs0, 16, 64); cs0 += __shfl_xor(cs0, 32, 64);
            cs1 += __shfl_xor(cs1, 16, 64); cs1 += __shfl_xor(cs1, 32, 64);
            if (lhi == 0) {
                cs_lds[wv][s * 32 + l15]      += cs0;
                cs_lds[wv][s * 32 + 16 + l15] += cs1;
            }
        } else {
#pragma unroll
            for (int r = 0; r < 4; ++r)
#pragma unroll
                for (int q = 0; q < 4; ++q) {
                    rs[r][q] += fexp2(KEXP2 * acc[r][0][q]) + fexp2(KEXP2 * acc[r][1][q]);
                }
        }

        if (s + 1 < NSTEP) {   // write next tile into the other buffer (linear)
#pragma unroll
            for (int i = 0; i < 4; ++i)
                ldsv[(buf ^ 1) * 1024 + tid + 256 * i] = st[i];
        }
        __syncthreads();
    }

    // row-sums: reduce over the 16 column-lanes, one atomic per row
#pragma unroll
    for (int r = 0; r < 4; ++r)
#pragma unroll
        for (int q = 0; q < 4; ++q) {
            float v = rs[r][q];
            v += __shfl_xor(v, 1, 64);
            v += __shfl_xor(v, 2, 64);
            v += __shfl_xor(v, 4, 64);
            v += __shfl_xor(v, 8, 64);
            if (l15 == 0)
                atomicAdd(&rowsum[i0 + wv * 64 + r * 16 + lhi * 4 + q], v);
        }

    // col-sums -> rows of tile tj (symmetry)
    if (!is_diag) {
        float cv = cs_lds[0][tid] + cs_lds[1][tid] + cs_lds[2][tid] + cs_lds[3][tid];
        atomicAdd(&rowsum[j0base + tid], cv);
    }
}

// Kernel 3: loss = (sum_i log(rowsum_i) - sum_b pos_partial_b) / N
__global__ void k_final(const float* __restrict__ rowsum, const float* __restrict__ pos_partial,
                        int n_partial, float* __restrict__ out, int N) {
    __shared__ float red[16];
    int lane = threadIdx.x & 63, wv = threadIdx.x >> 6;
    float local = 0.f;
    for (int i = threadIdx.x; i < N; i += 1024) local += __logf(rowsum[i]);
    for (int i = threadIdx.x; i < n_partial; i += 1024) local -= pos_partial[i];
#pragma unroll
    for (int off = 32; off >= 1; off >>= 1) local += __shfl_xor(local, off, 64);
    if (lane == 0) red[wv] = local;
    __syncthreads();
    if (threadIdx.x == 0) {
        float t = 0.f;
#pragma unroll
        for (int w = 0; w < 16; ++w) t += red[w];
        out[0] = t / (float)N;
    }
}

extern "C" void kernel_launch(void* const* d_in, const int* in_sizes, int n_in,
                              void* d_out, int out_size, void* d_ws, size_t ws_size,
                              hipStream_t stream) {
    const float* zi = (const float*)d_in[0];
    const float* zj = (const float*)d_in[1];
    const int B = in_sizes[0] / D;   // 4096
    const int N = 2 * B;             // 8192

    unsigned short* zn = (unsigned short*)d_ws;                       // N*D bf16 = 4 MB
    float* rowsum = (float*)((char*)d_ws + (size_t)N * D * 2);        // N floats
    float* pos_partial = rowsum + N;                                  // B/4 floats

    float* out = (float*)d_out;

    const int npb = B / 4;  // k_norm blocks == pos partials
    hipLaunchKernelGGL(k_norm, dim3(npb), dim3(256), 0, stream, zi, zj, zn, rowsum, pos_partial, B);
    hipLaunchKernelGGL(k_main, dim3(NBLK), dim3(256), 0, stream, zn, rowsum, N);
    hipLaunchKernelGGL(k_final, dim3(1), dim3(1024), 0, stream, rowsum, pos_partial, npb, out, N);
}